// Round 4
// baseline (253.365 us; speedup 1.0000x reference)
//
#include <hip/hip_runtime.h>
#include <hip/hip_bf16.h>
#include <stdint.h>

// DeepSeek MoE: rmsnorm+router -> grouped expert FFN (2 shared + 8 routed)
// R4: GEMM widened to BM=128 x BN=256, 8 waves (512 thr), BK=64 dbuf 2-phase
// (stage-issue-first), T2 src-swizzled LDS, tile-major XCD chunk.
// GEMM1 N and GEMM2 K zero-padded 1408->1536 (silu(0)=0 => pad contributes 0).

#define NTOK 2048
#define DM   1024
#define DH   1408
#define DHP  1536
#define NGRP 10
#define EPSV 1.1920928955078125e-7f
#define MAXTILES 72
#define MAXSLOTS (MAXTILES * 128)

typedef __bf16 bf16x8 __attribute__((ext_vector_type(8)));
typedef float  f32x4  __attribute__((ext_vector_type(4)));
typedef unsigned short u16x8 __attribute__((ext_vector_type(8)));

__device__ __forceinline__ void async16(const void* g, void* l) {
  __builtin_amdgcn_global_load_lds(
      (const __attribute__((address_space(1))) unsigned*)g,
      (__attribute__((address_space(3))) unsigned*)l, 16, 0, 0);
}

__device__ __forceinline__ unsigned short f2bf(float f) {
  unsigned u = __builtin_bit_cast(unsigned, f);
  unsigned r = (u + 0x7FFFu + ((u >> 16) & 1u)) >> 16;
  return (unsigned short)r;
}
__device__ __forceinline__ float bf2f(unsigned short h) {
  unsigned u = ((unsigned)h) << 16;
  return __builtin_bit_cast(float, u);
}

// bijective XCD-chunk swizzle (m204): consecutive LOGICAL ids -> same XCD
__device__ __forceinline__ int xcd_swizzle(int id, int nwg) {
  int q = nwg >> 3, r = nwg & 7;
  int xcd = id & 7, idx = id >> 3;
  return (xcd < r ? xcd * (q + 1) : r * (q + 1) + (xcd - r) * q) + idx;
}

// ---- fused transpose+convert with zero-padding ----
// z in [0,10):  W1-side f32 [1024][1408] -> bf16 [1536][1024], rows >=1408 zero
// z in [10,20): W2-side f32 [1408][1024] -> bf16 [1024][1536], cols >=1408 zero
__global__ __launch_bounds__(256) void transpose_conv(
    const float* __restrict__ Ws1, const float* __restrict__ W1,
    const float* __restrict__ Ws2, const float* __restrict__ W2,
    unsigned short* __restrict__ W1t, unsigned short* __restrict__ W2t) {
  __shared__ float t[64][65];
  int z = blockIdx.z, bx = blockIdx.x, by = blockIdx.y;
  const float* s; unsigned short* d; int C, dstride; bool zero;
  if (z < NGRP) {
    C = DH; dstride = DM;
    s = (z < 2) ? Ws1 + (size_t)z * DM * DH : W1 + (size_t)(z - 2) * DM * DH;
    d = W1t + (size_t)z * DHP * DM;
    if (by >= 16) return;          // R = 1024 -> 16 row-blocks
    zero = (bx >= 22);             // C pad region [1408,1536)
  } else {
    int g = z - NGRP;
    C = DM; dstride = DHP;
    s = (g < 2) ? Ws2 + (size_t)g * DH * DM : W2 + (size_t)(g - 2) * DH * DM;
    d = W2t + (size_t)g * DM * DHP;
    if (bx >= 16) return;          // C = 1024 -> 16 col-blocks
    zero = (by >= 22);             // R pad region [1408,1536)
  }
  int r0 = by * 64, c0 = bx * 64;
  int tid = threadIdx.x;
  if (!zero) {
    int rr = tid >> 4, c4 = tid & 15;
#pragma unroll
    for (int p = 0; p < 4; ++p) {
      float4 v = *(const float4*)(s + (size_t)(r0 + p * 16 + rr) * C + c0 + c4 * 4);
      t[p * 16 + rr][c4 * 4 + 0] = v.x;
      t[p * 16 + rr][c4 * 4 + 1] = v.y;
      t[p * 16 + rr][c4 * 4 + 2] = v.z;
      t[p * 16 + rr][c4 * 4 + 3] = v.w;
    }
  }
  __syncthreads();
  int c = tid >> 2;
#pragma unroll
  for (int q = 0; q < 2; ++q) {
    int oct = (tid & 3) * 2 + q;
    u16x8 uv;
#pragma unroll
    for (int j = 0; j < 8; ++j) uv[j] = zero ? (unsigned short)0 : f2bf(t[oct * 8 + j][c]);
    *(u16x8*)(d + (size_t)(c0 + c) * dstride + r0 + oct * 8) = uv;
  }
}

// ---- fused rmsnorm + router top2 ----
__global__ __launch_bounds__(256) void rmsnorm_router_k(
    const float* __restrict__ x, const float* __restrict__ nw, const float* __restrict__ Wr,
    unsigned short* __restrict__ xb, int* __restrict__ cnt,
    int* __restrict__ idx2, float* __restrict__ gate2) {
  int t = blockIdx.x, tid = threadIdx.x;
  const float4 v = *(const float4*)(x + (size_t)t * DM + tid * 4);
  float s = v.x * v.x + v.y * v.y + v.z * v.z + v.w * v.w;
#pragma unroll
  for (int o = 32; o; o >>= 1) s += __shfl_down(s, o);
  __shared__ float ps[4];
  if ((tid & 63) == 0) ps[tid >> 6] = s;
  __syncthreads();
  float tot = ps[0] + ps[1] + ps[2] + ps[3];
  float r = rsqrtf(tot * (1.0f / (float)DM) + EPSV);
  const float4 wv = *(const float4*)(nw + tid * 4);
  float4 y;
  y.x = v.x * r * wv.x; y.y = v.y * r * wv.y; y.z = v.z * r * wv.z; y.w = v.w * r * wv.w;
  ushort4 u; u.x = f2bf(y.x); u.y = f2bf(y.y); u.z = f2bf(y.z); u.w = f2bf(y.w);
  *(ushort4*)(xb + (size_t)t * DM + tid * 4) = u;
  float pr[8];
#pragma unroll
  for (int e = 0; e < 8; ++e) {
    const float4 w4 = *(const float4*)(Wr + (size_t)e * DM + tid * 4);
    pr[e] = y.x * w4.x + y.y * w4.y + y.z * w4.z + y.w * w4.w;
  }
#pragma unroll
  for (int e = 0; e < 8; ++e)
#pragma unroll
    for (int o = 32; o; o >>= 1) pr[e] += __shfl_down(pr[e], o);
  __shared__ float pw[4 * 8];
  if ((tid & 63) == 0) {
    int w = tid >> 6;
#pragma unroll
    for (int e = 0; e < 8; ++e) pw[w * 8 + e] = pr[e];
  }
  __syncthreads();
  if (tid == 0) {
    float af[8];
#pragma unroll
    for (int e = 0; e < 8; ++e) af[e] = pw[e] + pw[8 + e] + pw[16 + e] + pw[24 + e];
    int e1 = 0; float a1 = af[0];
#pragma unroll
    for (int e = 1; e < 8; ++e) if (af[e] > a1) { a1 = af[e]; e1 = e; }
    int e2 = -1; float a2 = -3.4e38f;
#pragma unroll
    for (int e = 0; e < 8; ++e) if (e != e1 && af[e] > a2) { a2 = af[e]; e2 = e; }
    atomicAdd(&cnt[e1], 1);
    atomicAdd(&cnt[e2], 1);
    idx2[t * 2] = e1; idx2[t * 2 + 1] = e2;
    gate2[t * 2] = a1; gate2[t * 2 + 1] = a2;
  }
}

// ---- build tile map + scatter tokens + padded bias tables ----
__global__ __launch_bounds__(256) void buildplace_k(
    const int* __restrict__ cnt, const int* __restrict__ idx2, const float* __restrict__ gate2,
    const float* __restrict__ bs1, const float* __restrict__ b1,
    const float* __restrict__ bs2, const float* __restrict__ b2,
    int* __restrict__ tile_group, int* __restrict__ tok_list, float* __restrict__ gate_list,
    int* __restrict__ slot_of, float* __restrict__ b1p, float* __restrict__ b2p) {
  __shared__ int base_s[8];
  __shared__ int fill_s[8];
  int tid = threadIdx.x;
  if (tid < 8) fill_s[tid] = 0;
  if (tid == 0) {
    for (int i = 0; i < 32; ++i) tile_group[i] = i >> 4;
    int tile = 32;
    for (int e = 0; e < 8; ++e) {
      base_s[e] = tile * 128;
      int nt = (cnt[e] + 127) >> 7;
      for (int i = 0; i < nt; ++i) tile_group[tile++] = 2 + e;
    }
    for (; tile < MAXTILES; ++tile) tile_group[tile] = -1;
  }
  for (int s = tid; s < MAXSLOTS; s += 256) {
    int tok; float gv;
    if (s < 2048)      { tok = s;        gv = 1.f; }
    else if (s < 4096) { tok = s - 2048; gv = 1.f; }
    else               { tok = -1;       gv = 0.f; }
    tok_list[s] = tok; gate_list[s] = gv;
  }
  for (int i = tid; i < NGRP * DHP; i += 256) {
    int gg = i / DHP, j = i % DHP;
    float v = 0.f;
    if (j < DH) v = (gg < 2) ? bs1[gg * DH + j] : b1[(gg - 2) * DH + j];
    b1p[i] = v;
  }
  for (int i = tid; i < NGRP * DM; i += 256) {
    int gg = i >> 10, j = i & (DM - 1);
    b2p[i] = (gg < 2) ? bs2[gg * DM + j] : b2[(gg - 2) * DM + j];
  }
  __syncthreads();
  for (int t = tid; t < NTOK; t += 256) {
#pragma unroll
    for (int k = 0; k < 2; ++k) {
      int e = idx2[t * 2 + k];
      int pos = atomicAdd(&fill_s[e], 1);
      int slot = base_s[e] + pos;
      tok_list[slot] = t;
      gate_list[slot] = gate2[t * 2 + k];
      slot_of[t * 2 + k] = slot;
    }
  }
}

// ---- grouped GEMM: 128x256 tile, 8 waves, BK=64, dbuf 2-phase, src-swizzled ----
template <int KD, int ND, int NBN, bool FIRST>
__global__ __launch_bounds__(512) void gemm_k(
    const unsigned short* __restrict__ A, const int* __restrict__ tok_list,
    const int* __restrict__ tile_group, const unsigned short* __restrict__ Bt,
    const float* __restrict__ biasP, const float* __restrict__ gate_list,
    unsigned short* __restrict__ Out) {
  constexpr int NK = KD / 64;
  int wg = xcd_swizzle(blockIdx.x, MAXTILES * NBN);
  int tile = wg / NBN;
  int bn = (wg % NBN) * 256;
  int g = tile_group[tile];
  if (g < 0) return;
  int tid = threadIdx.x;
  __shared__ unsigned short As[2][128 * 64];  // 16 KB each
  __shared__ unsigned short Bs[2][256 * 64];  // 32 KB each
  __shared__ int rows_s[128];
  __shared__ float gates_s[128];
  if (tid < 128) {
    if (FIRST) {
      int tok = tok_list[tile * 128 + tid];
      rows_s[tid] = tok < 0 ? 0 : tok;
    } else {
      gates_s[tid] = gate_list[tile * 128 + tid];
    }
  }
  __syncthreads();
  // staging: dest row = p*64 + (tid>>3), chunk16 = tid&7; value at (row,c16)
  // comes from global (row, c16 ^ (row&7))  [T2 involution]
  int drow = tid >> 3;
  int sc16 = (tid & 7) ^ (drow & 7);
  const unsigned short* bbase = Bt + ((size_t)g * ND + bn) * KD;
  const unsigned short* aSrc[2];
  const unsigned short* bSrc[4];
#pragma unroll
  for (int p = 0; p < 2; ++p) {
    int arow = p * 64 + drow;
    int grow = FIRST ? rows_s[arow] : tile * 128 + arow;
    aSrc[p] = A + (size_t)grow * KD + sc16 * 8;
  }
#pragma unroll
  for (int p = 0; p < 4; ++p)
    bSrc[p] = bbase + (size_t)(p * 64 + drow) * KD + sc16 * 8;

  int lane = tid & 63, w = tid >> 6;
  int wm = w >> 2, wn = w & 3;                 // 2 M-waves x 4 N-waves
  int lr = lane & 15, hi = lane >> 4, e8 = lr & 7;
  int offk0 = (hi ^ e8) * 16;
  int offk1 = ((4 + hi) ^ e8) * 16;
  f32x4 acc[4][4];
#pragma unroll
  for (int m = 0; m < 4; ++m)
#pragma unroll
    for (int n = 0; n < 4; ++n) acc[m][n] = (f32x4){0.f, 0.f, 0.f, 0.f};

  auto stage = [&](int buf, int kt) {
    int k0 = kt * 64;
#pragma unroll
    for (int p = 0; p < 2; ++p)
      async16(aSrc[p] + k0, (char*)&As[buf][0] + p * 8192 + tid * 16);
#pragma unroll
    for (int p = 0; p < 4; ++p)
      async16(bSrc[p] + k0, (char*)&Bs[buf][0] + p * 8192 + tid * 16);
  };
  stage(0, 0);
  __syncthreads();  // drains vmcnt(0): buf0 ready
  int cur = 0;
  for (int kt = 0; kt < NK; ++kt) {
    if (kt + 1 < NK) stage(cur ^ 1, kt + 1);  // issue-first, overlaps compute
    const char* aC = (const char*)&As[cur][0] + (wm * 64 + lr) * 128;
    const char* bC = (const char*)&Bs[cur][0] + (wn * 64 + lr) * 128;
#pragma unroll
    for (int ks = 0; ks < 2; ++ks) {
      int ofk = ks ? offk1 : offk0;
      bf16x8 a[4], b[4];
#pragma unroll
      for (int m = 0; m < 4; ++m) a[m] = *(const bf16x8*)(aC + m * 2048 + ofk);
#pragma unroll
      for (int n = 0; n < 4; ++n) b[n] = *(const bf16x8*)(bC + n * 2048 + ofk);
#pragma unroll
      for (int m = 0; m < 4; ++m)
#pragma unroll
        for (int n = 0; n < 4; ++n)
          acc[m][n] = __builtin_amdgcn_mfma_f32_16x16x32_bf16(a[m], b[n], acc[m][n], 0, 0, 0);
    }
    __syncthreads();  // next buffer staged; all reads of cur done
    cur ^= 1;
  }
  const float* bias = biasP + (size_t)g * ND;
#pragma unroll
  for (int n = 0; n < 4; ++n) {
    int gcol = bn + wn * 64 + n * 16 + lr;
    float bv = bias[gcol];
#pragma unroll
    for (int m = 0; m < 4; ++m) {
      int r0 = wm * 64 + m * 16 + hi * 4;
#pragma unroll
      for (int j = 0; j < 4; ++j) {
        float v = acc[m][n][j] + bv;
        if (FIRST) {
          v = v / (1.f + expf(-v));  // silu
        } else {
          v *= gates_s[r0 + j];
        }
        Out[(size_t)(tile * 128 + r0 + j) * ND + gcol] = f2bf(v);
      }
    }
  }
}

// ---- combine ----
__global__ __launch_bounds__(256) void combine_k(
    const float* __restrict__ x, const unsigned short* __restrict__ O,
    const int* __restrict__ slot_of, float* __restrict__ out) {
  int t = blockIdx.x, tid = threadIdx.x;
  int d = tid * 4;
  int s0 = slot_of[t * 2], s1 = slot_of[t * 2 + 1];
  float4 xv = *(const float4*)(x + (size_t)t * DM + d);
  ushort4 a = *(const ushort4*)(O + (size_t)t * DM + d);
  ushort4 b = *(const ushort4*)(O + (size_t)(2048 + t) * DM + d);
  ushort4 c = *(const ushort4*)(O + (size_t)s0 * DM + d);
  ushort4 e = *(const ushort4*)(O + (size_t)s1 * DM + d);
  float4 o;
  o.x = xv.x + bf2f(a.x) + bf2f(b.x) + bf2f(c.x) + bf2f(e.x);
  o.y = xv.y + bf2f(a.y) + bf2f(b.y) + bf2f(c.y) + bf2f(e.y);
  o.z = xv.z + bf2f(a.z) + bf2f(b.z) + bf2f(c.z) + bf2f(e.z);
  o.w = xv.w + bf2f(a.w) + bf2f(b.w) + bf2f(c.w) + bf2f(e.w);
  *(float4*)(out + (size_t)t * DM + d) = o;
}

extern "C" void kernel_launch(void* const* d_in, const int* in_sizes, int n_in,
                              void* d_out, int out_size, void* d_ws, size_t ws_size,
                              hipStream_t stream) {
  const float* x   = (const float*)d_in[0];
  const float* nw  = (const float*)d_in[1];
  const float* Wr  = (const float*)d_in[2];
  const float* Ws1 = (const float*)d_in[3];
  const float* bs1 = (const float*)d_in[4];
  const float* Ws2 = (const float*)d_in[5];
  const float* bs2 = (const float*)d_in[6];
  const float* W1  = (const float*)d_in[7];
  const float* b1  = (const float*)d_in[8];
  const float* W2  = (const float*)d_in[9];
  const float* b2  = (const float*)d_in[10];
  float* out = (float*)d_out;

  char* ws = (char*)d_ws;
  size_t off = 0;
  auto alloc = [&](size_t n) {
    size_t r = off;
    off += (n + 255) & ~(size_t)255;
    return r;
  };
  unsigned short* XnB  = (unsigned short*)(ws + alloc((size_t)NTOK * DM * 2));
  unsigned short* W1t  = (unsigned short*)(ws + alloc((size_t)NGRP * DHP * DM * 2));
  unsigned short* W2t  = (unsigned short*)(ws + alloc((size_t)NGRP * DM * DHP * 2));
  unsigned short* Hb   = (unsigned short*)(ws + alloc((size_t)MAXSLOTS * DHP * 2));
  unsigned short* Ob   = (unsigned short*)(ws + alloc((size_t)MAXSLOTS * DM * 2));
  int*   cnt       = (int*)(ws + alloc(64));
  int*   idx2      = (int*)(ws + alloc((size_t)NTOK * 2 * 4));
  float* gate2     = (float*)(ws + alloc((size_t)NTOK * 2 * 4));
  int*   tile_group= (int*)(ws + alloc(128 * 4));
  int*   tok_list  = (int*)(ws + alloc((size_t)MAXSLOTS * 4));
  float* gate_list = (float*)(ws + alloc((size_t)MAXSLOTS * 4));
  int*   slot_of   = (int*)(ws + alloc((size_t)NTOK * 2 * 4));
  float* b1p       = (float*)(ws + alloc((size_t)NGRP * DHP * 4));
  float* b2p       = (float*)(ws + alloc((size_t)NGRP * DM * 4));

  hipMemsetAsync(cnt, 0, 64, stream);

  transpose_conv<<<dim3(24, 24, 2 * NGRP), 256, 0, stream>>>(Ws1, W1, Ws2, W2, W1t, W2t);

  rmsnorm_router_k<<<NTOK, 256, 0, stream>>>(x, nw, Wr, XnB, cnt, idx2, gate2);
  buildplace_k<<<1, 256, 0, stream>>>(cnt, idx2, gate2, bs1, b1, bs2, b2,
                                      tile_group, tok_list, gate_list, slot_of, b1p, b2p);

  gemm_k<DM, DHP, 6, true><<<MAXTILES * 6, 512, 0, stream>>>(
      XnB, tok_list, tile_group, W1t, b1p, nullptr, Hb);
  gemm_k<DHP, DM, 4, false><<<MAXTILES * 4, 512, 0, stream>>>(
      Hb, tok_list, tile_group, W2t, b2p, gate_list, Ob);

  combine_k<<<NTOK, 256, 0, stream>>>(x, Ob, slot_of, out);
}